// Round 1
// 341.182 us; speedup vs baseline: 1.3743x; 1.3743x over previous
//
#include <hip/hip_runtime.h>
#include <stdint.h>

typedef int   int4v __attribute__((ext_vector_type(4)));
typedef float f32x4 __attribute__((ext_vector_type(4)));

// ---- workspace layout (bytes) ----
#define WS_SCALES 0ull
#define WS_ZERO   256ull
#define WS_BI1    1024ull
#define WS_BI2    2048ull
#define WS_BI3    4096ull
#define WS_BIS    8192ull
#define WS_W1Q    16384ull                     // int8 [256][512]
#define WS_W2Q    (WS_W1Q + 131072ull)         // int8 [256][2304]  k=(kh*3+kw)*256+c
#define WS_W3Q    (WS_W2Q + 589824ull)         // int8 [1024][256]
#define WS_WSQ    (WS_W3Q + 262144ull)         // int8 [1024][512]
#define WS_A0     2097152ull                   // int8 [50176][512]  (= [64][784][512])
#define WS_A1     (WS_A0 + 25690112ull)        // int8 [50176][256]
#define WS_A2     (WS_A1 + 12845056ull)        // int8 [12544][256]  (= [64][196][256])

__device__ __forceinline__ void gll16(const void* g, void* l) {
    // async global -> LDS, 16B/lane, dest = wave-uniform base + lane*16
    __builtin_amdgcn_global_load_lds((const __attribute__((address_space(1))) void*)g,
                                     (__attribute__((address_space(3))) void*)l, 16, 0, 0);
}

__global__ void k_init(float* wshead) {
    int i = blockIdx.x * 256 + threadIdx.x;
    wshead[i] = 0.0f;   // 16 blocks x 256 = 16 KB: scales+zero page+biases
}

__global__ void k_maxabs(const float* __restrict__ w1, const float* __restrict__ w2,
                         const float* __restrict__ w3, const float* __restrict__ wsd,
                         float* __restrict__ scales) {
    const float* srcs[4] = {w1, w2, w3, wsd};
    const int ns[4] = {131072, 589824, 262144, 524288};
    int t = blockIdx.y;
    const float* s = srcs[t];
    int n = ns[t];
    float m = 0.0f;
    for (int i = blockIdx.x * 256 + threadIdx.x; i < n; i += gridDim.x * 256)
        m = fmaxf(m, fabsf(s[i]));
    __shared__ float red[256];
    red[threadIdx.x] = m;
    __syncthreads();
    for (int st = 128; st > 0; st >>= 1) {
        if (threadIdx.x < st) red[threadIdx.x] = fmaxf(red[threadIdx.x], red[threadIdx.x + st]);
        __syncthreads();
    }
    if (threadIdx.x == 0) atomicMax((int*)&scales[t], __float_as_int(red[0]));
}

__global__ void k_quant_w(const float* __restrict__ w1, const float* __restrict__ w2,
                          const float* __restrict__ w3, const float* __restrict__ wsd,
                          const float* __restrict__ b1, const float* __restrict__ b2,
                          const float* __restrict__ b3, const float* __restrict__ bs,
                          char* __restrict__ wsb) {
    const float* sc = (const float*)(wsb + WS_SCALES);
    int mode = blockIdx.y;
    int i0 = blockIdx.x * 256 + threadIdx.x;
    int stride = gridDim.x * 256;
    if (mode == 0) {
        float s = sc[0]; signed char* o = (signed char*)(wsb + WS_W1Q);
        for (int i = i0; i < 131072; i += stride)
            o[i] = (signed char)(int)rintf(fminf(fmaxf(w1[i] / s, -1.f), 1.f) * 127.f);
    } else if (mode == 1) {
        float s = sc[1]; signed char* o = (signed char*)(wsb + WS_W2Q);
        for (int i = i0; i < 589824; i += stride) {
            int oo = i / 2304, r2 = i - oo * 2304;
            int c = r2 / 9, kk = r2 - c * 9;
            o[(size_t)oo * 2304 + kk * 256 + c] =
                (signed char)(int)rintf(fminf(fmaxf(w2[i] / s, -1.f), 1.f) * 127.f);
        }
    } else if (mode == 2) {
        float s = sc[2]; signed char* o = (signed char*)(wsb + WS_W3Q);
        for (int i = i0; i < 262144; i += stride)
            o[i] = (signed char)(int)rintf(fminf(fmaxf(w3[i] / s, -1.f), 1.f) * 127.f);
    } else if (mode == 3) {
        float s = sc[3]; signed char* o = (signed char*)(wsb + WS_WSQ);
        for (int i = i0; i < 524288; i += stride)
            o[i] = (signed char)(int)rintf(fminf(fmaxf(wsd[i] / s, -1.f), 1.f) * 127.f);
    } else if (mode == 4) {
        float* o = (float*)(wsb + WS_BI1);
        for (int i = i0; i < 256; i += stride) o[i] = rintf(b1[i] * 127.f);
    } else if (mode == 5) {
        float* o = (float*)(wsb + WS_BI2);
        for (int i = i0; i < 256; i += stride) o[i] = rintf(b2[i] * 127.f);
    } else if (mode == 6) {
        float* o = (float*)(wsb + WS_BI3);
        for (int i = i0; i < 1024; i += stride) o[i] = rintf(b3[i] * 127.f);
    } else {
        float* o = (float*)(wsb + WS_BIS);
        for (int i = i0; i < 1024; i += stride) o[i] = rintf(bs[i] * 127.f);
    }
}

// quantize + transpose x: float [64][512][784] -> int8 a0 [64*784][512]
__global__ void k_quant_x(const float* __restrict__ x, signed char* __restrict__ a0) {
    __shared__ signed char tile[32][33];
    int b = blockIdx.z;
    int p0 = blockIdx.x * 32, c0 = blockIdx.y * 32;
    int tp = threadIdx.x & 31, tr = threadIdx.x >> 5;
    const float* xb = x + ((size_t)b * 512 + c0) * 784 + p0;
    for (int i = 0; i < 4; i++) {
        int cc = tr + i * 8;
        float v = (p0 + tp < 784) ? xb[(size_t)cc * 784 + tp] : 0.f;
        v = fminf(fmaxf(v * 2.f, -1.f), 1.f);
        tile[cc][tp] = (signed char)(int)rintf(v * 127.f);
    }
    __syncthreads();
    // out: 4 consecutive c per thread -> 4B stores, 32B contiguous per 8 lanes
    int pp = threadIdx.x >> 3, cs = (threadIdx.x & 7) * 4;
    if (p0 + pp < 784) {
        unsigned pk = 0;
        for (int i = 0; i < 4; i++)
            pk |= (unsigned)(unsigned char)tile[cs + i][pp] << (8 * i);
        *(unsigned*)(a0 + ((size_t)b * 784 + p0 + pp) * 512 + c0 + cs) = pk;
    }
}

// ---------- i8-MFMA GEMM kernels ----------
// MODE 0: conv1  M=256 K=512  Nflat=50176 -> a1 int8 [n][256]
// MODE 1: conv2  M=256 K=2304 Nflat=12544 (im2col 3x3/s2/p1 gather) -> a2 int8 [n][256]
// MODE 2: conv3 (t<4: K=256 a2) + shortcut (t>=4: K=512 a0 strided) -> float out NCHW
//
// Staging: global_load_lds dwordx4, LDS double-buffered, 1 barrier per K-step.
// Bank swizzle moved to the SOURCE side (rule #21): LDS dest linear (lane*16),
// each lane loads global chunk (schunk ^ ((srow>>1)&3)); reads keep the XOR.
template <int MODE, int BM, int BN, int WGM, int WGN>
__global__ __launch_bounds__(256) void k_conv(char* __restrict__ wsb, float* __restrict__ dout) {
    constexpr int FM = BM / WGM / 16;
    constexpr int FN = BN / WGN / 16;
    constexpr int ISS_A = BM / 16;
    constexpr int NISS = (BM + BN) / 16;
    constexpr int NI = NISS / 4;
    constexpr int KTOT = (MODE == 0) ? 512 : (MODE == 1) ? 2304 : 768;
    constexpr int NSTEP = KTOT / 64;
    constexpr int BMP = BM + 16;                     // padded epi stride (int8 modes)
    constexpr int LDS_STAGE = (BM + BN) * 64;        // one staging buffer
    constexpr int LDS_EPI = (MODE == 2) ? 64 * (BN + 4) * 4 : BN * BMP;
    constexpr int LDSZ = (2 * LDS_STAGE > LDS_EPI) ? 2 * LDS_STAGE : LDS_EPI;

    __shared__ alignas(16) char lds[LDSZ];

    const int tid = threadIdx.x;
    const int wid = tid >> 6;
    const int lane = tid & 63;
    const int n0 = blockIdx.x * BN;
    const int m0 = blockIdx.y * BM;
    const int bb = blockIdx.z;

    const float* sc = (const float*)(wsb + WS_SCALES);
    const int srow = lane >> 2;
    const int lrow = lane & 15;
    const int quad = lane >> 4;
    const int wm = (wid % WGM) * (BM / WGM);
    const int wn = (wid / WGM) * (BN / WGN);
    // source-side chunk swizzle: lane loads global chunk (schunk ^ ((srow>>1)&3))
    const int xco = ((lane & 3) ^ ((lane >> 3) & 3)) << 4;
    const char* zp = wsb + WS_ZERO + xco;

    int4v acc3[FM][FN] = {};
    int4v accS[FM][FN] = {};

    auto src_ptr = [&](int s, int k0) -> const char* {
        const char* g;
        if (s < ISS_A) {
            int m = m0 + s * 16 + srow;
            if (MODE == 0)
                g = wsb + WS_W1Q + (size_t)m * 512 + k0 + xco;
            else if (MODE == 1)
                g = wsb + WS_W2Q + (size_t)m * 2304 + k0 + xco;
            else
                g = (k0 < 256) ? wsb + WS_W3Q + (size_t)m * 256 + k0 + xco
                               : wsb + WS_WSQ + (size_t)m * 512 + (k0 - 256) + xco;
        } else {
            int n = n0 + (s - ISS_A) * 16 + srow;
            g = zp;
            if (MODE == 0) {
                g = wsb + WS_A0 + (size_t)n * 512 + k0 + xco;
            } else if (MODE == 1) {
                unsigned b = (unsigned)n / 196u;
                unsigned hw = (unsigned)n - b * 196u;
                int oh = hw / 14, ow = hw - oh * 14;
                int tap = k0 >> 8;
                int kh = tap / 3, kw = tap - kh * 3;
                int c0 = k0 & 255;
                int ih = 2 * oh - 1 + kh, iw = 2 * ow - 1 + kw;
                if (ih >= 0 && ih < 28 && iw >= 0 && iw < 28)
                    g = wsb + WS_A1 + ((size_t)b * 784 + ih * 28 + iw) * 256 + c0 + xco;
            } else {
                if (n < 196) {
                    if (k0 < 256) {
                        g = wsb + WS_A2 + ((size_t)bb * 196 + n) * 256 + k0 + xco;
                    } else {
                        int oh = n / 14, ow = n - oh * 14;
                        int ps = oh * 56 + ow * 2;
                        g = wsb + WS_A0 + ((size_t)bb * 784 + ps) * 512 + (k0 - 256) + xco;
                    }
                }
            }
        }
        return g;
    };

    auto stage = [&](int t, char* buf) {
        const int k0 = t * 64;
#pragma unroll
        for (int ii = 0; ii < NI; ii++) {
            const int s = wid + ii * 4;
            gll16(src_ptr(s, k0), buf + s * 1024);   // lds dest wave-uniform, linear
        }
    };

    stage(0, lds);                                   // prologue prefetch into buf0
    for (int t = 0; t < NSTEP; ++t) {
        char* cur = lds + (t & 1) * LDS_STAGE;
        char* nxt = lds + ((t & 1) ^ 1) * LDS_STAGE;
        __syncthreads();                 // vmcnt(0)+barrier: cur ready, nxt reads done
        if (t + 1 < NSTEP) stage(t + 1, nxt);        // prefetch flies across compute

        int4v afr[FM], bfr[FN];
#pragma unroll
        for (int i = 0; i < FM; i++) {
            int m = wm + i * 16 + lrow;
            afr[i] = *(const int4v*)(cur + m * 64 + ((quad ^ ((m >> 1) & 3)) << 4));
        }
#pragma unroll
        for (int j = 0; j < FN; j++) {
            int n = wn + j * 16 + lrow;
            bfr[j] = *(const int4v*)(cur + (BM + n) * 64 + ((quad ^ ((n >> 1) & 3)) << 4));
        }
        if (MODE != 2 || t < 4) {
#pragma unroll
            for (int i = 0; i < FM; i++)
#pragma unroll
                for (int j = 0; j < FN; j++)
                    acc3[i][j] = __builtin_amdgcn_mfma_i32_16x16x64_i8(afr[i], bfr[j], acc3[i][j], 0, 0, 0);
        } else {
#pragma unroll
            for (int i = 0; i < FM; i++)
#pragma unroll
                for (int j = 0; j < FN; j++)
                    accS[i][j] = __builtin_amdgcn_mfma_i32_16x16x64_i8(afr[i], bfr[j], accS[i][j], 0, 0, 0);
        }
    }

    // ---------------- epilogue (C/D map: col=lane&15, row=quad*4+reg) ----------------
    if (MODE == 0 || MODE == 1) {
        const float alpha = sc[MODE] / 16129.0f;
        const float* bi = (const float*)(wsb + (MODE == 0 ? WS_BI1 : WS_BI2));
        signed char* outp = (signed char*)(wsb + (MODE == 0 ? WS_A1 : WS_A2));
        __syncthreads();   // staging reads finished everywhere
#pragma unroll
        for (int i = 0; i < FM; i++) {
            int mloc = wm + i * 16 + quad * 4;      // local m of r=0
            int mb = m0 + mloc;
            float bt[4];
#pragma unroll
            for (int r = 0; r < 4; r++) bt[r] = bi[mb + r] * (2.0f / 127.0f);
#pragma unroll
            for (int j = 0; j < FN; j++) {
                int nloc = wn + j * 16 + lrow;
                unsigned pk = 0;
#pragma unroll
                for (int r = 0; r < 4; r++) {
                    float v = alpha * (float)acc3[i][j][r] + bt[r];
                    int q = (int)rintf(127.0f * fminf(fmaxf(2.0f * v, 0.0f), 1.0f));
                    pk |= (unsigned)(q & 0xFF) << (8 * r);
                }
                *(unsigned*)(lds + nloc * BMP + mloc) = pk;
            }
        }
        __syncthreads();
        // coalesced copy-out: full 64B-line coverage, rows are [n][256] m-contig
        for (int u = tid; u < BN * (BM / 16); u += 256) {
            int row = u / (BM / 16);
            int seg = u % (BM / 16);
            uint4 v = *(const uint4*)(lds + row * BMP + seg * 16);
            *(uint4*)(outp + (size_t)(n0 + row) * 256 + m0 + seg * 16) = v;
        }
    } else {
        const float c2 = sc[1], c3 = sc[2], cS = sc[3];
        const float* bi3 = (const float*)(wsb + WS_BI3);
        const float* bis = (const float*)(wsb + WS_BIS);
        float* ldsF = (float*)lds;
        constexpr int LDN = BN + 4;
        constexpr int SEGS = BN / 16;
        for (int half = 0; half < 2; half++) {
            __syncthreads();
            if (wm == half * 64) {
#pragma unroll
                for (int i = 0; i < FM; i++) {
                    int mloc = i * 16 + quad * 4;           // within half [0,64)
                    int mg = m0 + half * 64 + mloc;         // global m
                    float bt[4];
#pragma unroll
                    for (int r = 0; r < 4; r++)
                        bt[r] = bi3[mg + r] * (c3 / (127.0f * c2)) + bis[mg + r] * (1.0f / 127.0f);
#pragma unroll
                    for (int j = 0; j < FN; j++) {
                        int nloc = wn + j * 16 + lrow;
#pragma unroll
                        for (int r = 0; r < 4; r++) {
                            float v = (c3 * (float)acc3[i][j][r] + cS * (float)accS[i][j][r])
                                          * (0.5f / 16129.0f) + bt[r];
                            v = v < 0.0f ? 0.0f : (v > 6.0f ? 6.0f : v);  // NaN-propagating
                            ldsF[(mloc + r) * LDN + nloc] = v;
                        }
                    }
                }
            }
            __syncthreads();
            // copy out 64 rows x BN floats (aligned 16B segments along n)
            {
                int rw0 = tid / SEGS, seg = tid % SEGS;
                int nbase = n0 + seg * 16;
                for (int row = rw0; row < 64; row += 256 / SEGS) {
                    const float* src = ldsF + row * LDN + seg * 16;
                    float* dst = dout + ((size_t)bb * 1024 + m0 + half * 64 + row) * 196 + nbase;
                    if (nbase + 16 <= 196) {
                        *(f32x4*)(dst + 0)  = *(const f32x4*)(src + 0);
                        *(f32x4*)(dst + 4)  = *(const f32x4*)(src + 4);
                        *(f32x4*)(dst + 8)  = *(const f32x4*)(src + 8);
                        *(f32x4*)(dst + 12) = *(const f32x4*)(src + 12);
                    } else {
                        for (int q = 0; q < 16 && nbase + q < 196; q++) dst[q] = src[q];
                    }
                }
            }
        }
    }
}

extern "C" void kernel_launch(void* const* d_in, const int* in_sizes, int n_in,
                              void* d_out, int out_size, void* d_ws, size_t ws_size,
                              hipStream_t stream) {
    const float* x   = (const float*)d_in[0];
    const float* w1  = (const float*)d_in[1];
    const float* b1  = (const float*)d_in[2];
    const float* w2  = (const float*)d_in[3];
    const float* b2  = (const float*)d_in[4];
    const float* w3  = (const float*)d_in[5];
    const float* b3  = (const float*)d_in[6];
    const float* wsd = (const float*)d_in[7];
    const float* bs  = (const float*)d_in[8];
    float* out = (float*)d_out;
    char* wsb = (char*)d_ws;

    k_init<<<16, 256, 0, stream>>>((float*)wsb);
    k_maxabs<<<dim3(32, 4), 256, 0, stream>>>(w1, w2, w3, wsd, (float*)(wsb + WS_SCALES));
    k_quant_w<<<dim3(96, 8), 256, 0, stream>>>(w1, w2, w3, wsd, b1, b2, b3, bs, wsb);
    k_quant_x<<<dim3(25, 16, 64), 256, 0, stream>>>(x, (signed char*)(wsb + WS_A0));
    k_conv<0, 128, 128, 2, 2><<<dim3(392, 2, 1), 256, 0, stream>>>(wsb, out);  // conv1
    k_conv<1, 64, 128, 2, 2><<<dim3(98, 4, 1), 256, 0, stream>>>(wsb, out);    // conv2
    k_conv<2, 128, 128, 2, 2><<<dim3(2, 8, 64), 256, 0, stream>>>(wsb, out);   // conv3+sc
}

// Round 2
// 328.695 us; speedup vs baseline: 1.4265x; 1.0380x over previous
//
#include <hip/hip_runtime.h>
#include <stdint.h>

typedef int   int4v __attribute__((ext_vector_type(4)));
typedef float f32x4 __attribute__((ext_vector_type(4)));

// ---- workspace layout (bytes) ----
#define WS_SCALES 0ull
#define WS_ZERO   256ull
#define WS_BI1    1024ull
#define WS_BI2    2048ull
#define WS_BI3    4096ull
#define WS_BIS    8192ull
#define WS_W1Q    16384ull                     // int8 [256][512]
#define WS_W2Q    (WS_W1Q + 131072ull)         // int8 [256][2304]  k=(kh*3+kw)*256+c
#define WS_W3Q    (WS_W2Q + 589824ull)         // int8 [1024][256]
#define WS_WSQ    (WS_W3Q + 262144ull)         // int8 [1024][512]
#define WS_A0     2097152ull                   // int8 [50176][512]  (= [64][784][512])
#define WS_A1     (WS_A0 + 25690112ull)        // int8 [50176][256]
#define WS_A2     (WS_A1 + 12845056ull)        // int8 [12544][256]  (= [64][196][256])

__device__ __forceinline__ void gll16(const void* g, void* l) {
    // async global -> LDS, 16B/lane, dest = wave-uniform base + lane*16
    __builtin_amdgcn_global_load_lds((const __attribute__((address_space(1))) void*)g,
                                     (__attribute__((address_space(3))) void*)l, 16, 0, 0);
}

// counted-wait + raw barrier (T4): leave n vmem ops in flight across the barrier.
// "memory" clobber pins LDS reads/writes and global_load_lds issue order around it.
#define VMCNT_BAR(n) asm volatile("s_waitcnt vmcnt(" #n ")\n\ts_barrier" ::: "memory")

__global__ void k_init(float* wshead) {
    int i = blockIdx.x * 256 + threadIdx.x;
    wshead[i] = 0.0f;   // 16 blocks x 256 = 16 KB: scales+zero page+biases
}

__global__ void k_maxabs(const float* __restrict__ w1, const float* __restrict__ w2,
                         const float* __restrict__ w3, const float* __restrict__ wsd,
                         float* __restrict__ scales) {
    const float* srcs[4] = {w1, w2, w3, wsd};
    const int ns[4] = {131072, 589824, 262144, 524288};
    int t = blockIdx.y;
    const float* s = srcs[t];
    int n = ns[t];
    float m = 0.0f;
    for (int i = blockIdx.x * 256 + threadIdx.x; i < n; i += gridDim.x * 256)
        m = fmaxf(m, fabsf(s[i]));
    __shared__ float red[256];
    red[threadIdx.x] = m;
    __syncthreads();
    for (int st = 128; st > 0; st >>= 1) {
        if (threadIdx.x < st) red[threadIdx.x] = fmaxf(red[threadIdx.x], red[threadIdx.x + st]);
        __syncthreads();
    }
    if (threadIdx.x == 0) atomicMax((int*)&scales[t], __float_as_int(red[0]));
}

__global__ void k_quant_w(const float* __restrict__ w1, const float* __restrict__ w2,
                          const float* __restrict__ w3, const float* __restrict__ wsd,
                          const float* __restrict__ b1, const float* __restrict__ b2,
                          const float* __restrict__ b3, const float* __restrict__ bs,
                          char* __restrict__ wsb) {
    const float* sc = (const float*)(wsb + WS_SCALES);
    int mode = blockIdx.y;
    int i0 = blockIdx.x * 256 + threadIdx.x;
    int stride = gridDim.x * 256;
    if (mode == 0) {
        float s = sc[0]; signed char* o = (signed char*)(wsb + WS_W1Q);
        for (int i = i0; i < 131072; i += stride)
            o[i] = (signed char)(int)rintf(fminf(fmaxf(w1[i] / s, -1.f), 1.f) * 127.f);
    } else if (mode == 1) {
        float s = sc[1]; signed char* o = (signed char*)(wsb + WS_W2Q);
        for (int i = i0; i < 589824; i += stride) {
            int oo = i / 2304, r2 = i - oo * 2304;
            int c = r2 / 9, kk = r2 - c * 9;
            o[(size_t)oo * 2304 + kk * 256 + c] =
                (signed char)(int)rintf(fminf(fmaxf(w2[i] / s, -1.f), 1.f) * 127.f);
        }
    } else if (mode == 2) {
        float s = sc[2]; signed char* o = (signed char*)(wsb + WS_W3Q);
        for (int i = i0; i < 262144; i += stride)
            o[i] = (signed char)(int)rintf(fminf(fmaxf(w3[i] / s, -1.f), 1.f) * 127.f);
    } else if (mode == 3) {
        float s = sc[3]; signed char* o = (signed char*)(wsb + WS_WSQ);
        for (int i = i0; i < 524288; i += stride)
            o[i] = (signed char)(int)rintf(fminf(fmaxf(wsd[i] / s, -1.f), 1.f) * 127.f);
    } else if (mode == 4) {
        float* o = (float*)(wsb + WS_BI1);
        for (int i = i0; i < 256; i += stride) o[i] = rintf(b1[i] * 127.f);
    } else if (mode == 5) {
        float* o = (float*)(wsb + WS_BI2);
        for (int i = i0; i < 256; i += stride) o[i] = rintf(b2[i] * 127.f);
    } else if (mode == 6) {
        float* o = (float*)(wsb + WS_BI3);
        for (int i = i0; i < 1024; i += stride) o[i] = rintf(b3[i] * 127.f);
    } else {
        float* o = (float*)(wsb + WS_BIS);
        for (int i = i0; i < 1024; i += stride) o[i] = rintf(bs[i] * 127.f);
    }
}

// quantize + transpose x: float [64][512][784] -> int8 a0 [64*784][512]
__global__ void k_quant_x(const float* __restrict__ x, signed char* __restrict__ a0) {
    __shared__ signed char tile[32][33];
    int b = blockIdx.z;
    int p0 = blockIdx.x * 32, c0 = blockIdx.y * 32;
    int tp = threadIdx.x & 31, tr = threadIdx.x >> 5;
    const float* xb = x + ((size_t)b * 512 + c0) * 784 + p0;
    for (int i = 0; i < 4; i++) {
        int cc = tr + i * 8;
        float v = (p0 + tp < 784) ? xb[(size_t)cc * 784 + tp] : 0.f;
        v = fminf(fmaxf(v * 2.f, -1.f), 1.f);
        tile[cc][tp] = (signed char)(int)rintf(v * 127.f);
    }
    __syncthreads();
    // out: 4 consecutive c per thread -> 4B stores, 32B contiguous per 8 lanes
    int pp = threadIdx.x >> 3, cs = (threadIdx.x & 7) * 4;
    if (p0 + pp < 784) {
        unsigned pk = 0;
        for (int i = 0; i < 4; i++)
            pk |= (unsigned)(unsigned char)tile[cs + i][pp] << (8 * i);
        *(unsigned*)(a0 + ((size_t)b * 784 + p0 + pp) * 512 + c0 + cs) = pk;
    }
}

// ---------- i8-MFMA GEMM kernels ----------
// MODE 0: conv1  M=256 K=512  Nflat=50176 -> a1 int8 [n][256]
// MODE 1: conv2  M=256 K=2304 Nflat=12544 (im2col 3x3/s2/p1 gather) -> a2 int8 [n][256]
// MODE 2: conv3 (t<4: K=256 a2) + shortcut (t>=4: K=512 a0 strided) -> float out NCHW
//
// Staging: global_load_lds dwordx4 into 3 rotating LDS buffers, prefetch depth 2,
// counted vmcnt(NI) + raw s_barrier per K-step (never drain to 0 in the main loop).
// Sync-safety derivation:
//  * tile-t LDS writes complete at barrier(t) release: each wave's vmcnt(NI)
//    retires its own NI tile-t loads (the NI newest in flight are tile t+1's),
//    then all waves barrier.
//  * stage(t+2) overwrites buf[(t+2)%3] == buf[(t-1)%3]; its readers (step t-1
//    ds_reads) were consumed by MFMA (lgkmcnt) before each wave arrived at
//    barrier(t), and stage(t+2) issues only after barrier(t) releases.
//  * last iteration peeled with vmcnt(0): otherwise the final tile's own loads
//    would be the "allowed in flight" ones.
// Bank swizzle is on the SOURCE side (rule #21): LDS dest linear (lane*16),
// each lane loads global chunk (schunk ^ ((srow>>1)&3)); reads keep the XOR.
template <int MODE, int BM, int BN, int WGM, int WGN>
__global__ __launch_bounds__(256) void k_conv(char* __restrict__ wsb, float* __restrict__ dout) {
    constexpr int FM = BM / WGM / 16;
    constexpr int FN = BN / WGN / 16;
    constexpr int ISS_A = BM / 16;
    constexpr int NISS = (BM + BN) / 16;
    constexpr int NI = NISS / 4;
    constexpr int KTOT = (MODE == 0) ? 512 : (MODE == 1) ? 2304 : 768;
    constexpr int NSTEP = KTOT / 64;
    constexpr int BMP = BM + 16;                     // padded epi stride (int8 modes)
    constexpr int LDS_STAGE = (BM + BN) * 64;        // one staging buffer
    constexpr int LDS_EPI = (MODE == 2) ? 64 * (BN + 4) * 4 : BN * BMP;
    constexpr int LDSZ = (3 * LDS_STAGE > LDS_EPI) ? 3 * LDS_STAGE : LDS_EPI;

    __shared__ alignas(16) char lds[LDSZ];

    const int tid = threadIdx.x;
    const int wid = tid >> 6;
    const int lane = tid & 63;
    const int n0 = blockIdx.x * BN;
    const int m0 = blockIdx.y * BM;
    const int bb = blockIdx.z;

    const float* sc = (const float*)(wsb + WS_SCALES);
    const int srow = lane >> 2;
    const int lrow = lane & 15;
    const int quad = lane >> 4;
    const int wm = (wid % WGM) * (BM / WGM);
    const int wn = (wid / WGM) * (BN / WGN);
    // source-side chunk swizzle: lane loads global chunk (schunk ^ ((srow>>1)&3))
    const int xco = ((lane & 3) ^ ((lane >> 3) & 3)) << 4;
    const char* zp = wsb + WS_ZERO + xco;

    int4v acc3[FM][FN] = {};
    int4v accS[FM][FN] = {};

    auto src_ptr = [&](int s, int k0) -> const char* {
        const char* g;
        if (s < ISS_A) {
            int m = m0 + s * 16 + srow;
            if (MODE == 0)
                g = wsb + WS_W1Q + (size_t)m * 512 + k0 + xco;
            else if (MODE == 1)
                g = wsb + WS_W2Q + (size_t)m * 2304 + k0 + xco;
            else
                g = (k0 < 256) ? wsb + WS_W3Q + (size_t)m * 256 + k0 + xco
                               : wsb + WS_WSQ + (size_t)m * 512 + (k0 - 256) + xco;
        } else {
            int n = n0 + (s - ISS_A) * 16 + srow;
            g = zp;
            if (MODE == 0) {
                g = wsb + WS_A0 + (size_t)n * 512 + k0 + xco;
            } else if (MODE == 1) {
                unsigned b = (unsigned)n / 196u;
                unsigned hw = (unsigned)n - b * 196u;
                int oh = hw / 14, ow = hw - oh * 14;
                int tap = k0 >> 8;
                int kh = tap / 3, kw = tap - kh * 3;
                int c0 = k0 & 255;
                int ih = 2 * oh - 1 + kh, iw = 2 * ow - 1 + kw;
                if (ih >= 0 && ih < 28 && iw >= 0 && iw < 28)
                    g = wsb + WS_A1 + ((size_t)b * 784 + ih * 28 + iw) * 256 + c0 + xco;
            } else {
                if (n < 196) {
                    if (k0 < 256) {
                        g = wsb + WS_A2 + ((size_t)bb * 196 + n) * 256 + k0 + xco;
                    } else {
                        int oh = n / 14, ow = n - oh * 14;
                        int ps = oh * 56 + ow * 2;
                        g = wsb + WS_A0 + ((size_t)bb * 784 + ps) * 512 + (k0 - 256) + xco;
                    }
                }
            }
        }
        return g;
    };

    auto stage = [&](int t, char* buf) {
        const int k0 = t * 64;
#pragma unroll
        for (int ii = 0; ii < NI; ii++) {
            const int s = wid + ii * 4;
            gll16(src_ptr(s, k0), buf + s * 1024);   // lds dest wave-uniform, linear
        }
    };

    stage(0, lds);
    stage(1, lds + LDS_STAGE);                       // prefetch depth 2
    for (int t = 0; t < NSTEP; ++t) {
        char* cur = lds + (t % 3) * LDS_STAGE;
        if (t == NSTEP - 1) {
            VMCNT_BAR(0);                            // peeled: drain own final tile
        } else if constexpr (NI == 3) {
            VMCNT_BAR(3);                            // tile t done; t+1's 3 in flight
        } else {
            VMCNT_BAR(4);                            // tile t done; t+1's 4 in flight
        }
        if (t + 2 < NSTEP) stage(t + 2, lds + ((t + 2) % 3) * LDS_STAGE);

        int4v afr[FM], bfr[FN];
#pragma unroll
        for (int i = 0; i < FM; i++) {
            int m = wm + i * 16 + lrow;
            afr[i] = *(const int4v*)(cur + m * 64 + ((quad ^ ((m >> 1) & 3)) << 4));
        }
#pragma unroll
        for (int j = 0; j < FN; j++) {
            int n = wn + j * 16 + lrow;
            bfr[j] = *(const int4v*)(cur + (BM + n) * 64 + ((quad ^ ((n >> 1) & 3)) << 4));
        }
        if (MODE != 2 || t < 4) {
#pragma unroll
            for (int i = 0; i < FM; i++)
#pragma unroll
                for (int j = 0; j < FN; j++)
                    acc3[i][j] = __builtin_amdgcn_mfma_i32_16x16x64_i8(afr[i], bfr[j], acc3[i][j], 0, 0, 0);
        } else {
#pragma unroll
            for (int i = 0; i < FM; i++)
#pragma unroll
                for (int j = 0; j < FN; j++)
                    accS[i][j] = __builtin_amdgcn_mfma_i32_16x16x64_i8(afr[i], bfr[j], accS[i][j], 0, 0, 0);
        }
    }

    // ---------------- epilogue (C/D map: col=lane&15, row=quad*4+reg) ----------------
    if (MODE == 0 || MODE == 1) {
        const float alpha = sc[MODE] / 16129.0f;
        const float* bi = (const float*)(wsb + (MODE == 0 ? WS_BI1 : WS_BI2));
        signed char* outp = (signed char*)(wsb + (MODE == 0 ? WS_A1 : WS_A2));
        __syncthreads();   // staging reads finished everywhere
#pragma unroll
        for (int i = 0; i < FM; i++) {
            int mloc = wm + i * 16 + quad * 4;      // local m of r=0
            int mb = m0 + mloc;
            float bt[4];
#pragma unroll
            for (int r = 0; r < 4; r++) bt[r] = bi[mb + r] * (2.0f / 127.0f);
#pragma unroll
            for (int j = 0; j < FN; j++) {
                int nloc = wn + j * 16 + lrow;
                unsigned pk = 0;
#pragma unroll
                for (int r = 0; r < 4; r++) {
                    float v = alpha * (float)acc3[i][j][r] + bt[r];
                    int q = (int)rintf(127.0f * fminf(fmaxf(2.0f * v, 0.0f), 1.0f));
                    pk |= (unsigned)(q & 0xFF) << (8 * r);
                }
                *(unsigned*)(lds + nloc * BMP + mloc) = pk;
            }
        }
        __syncthreads();
        // coalesced copy-out: full 64B-line coverage, rows are [n][256] m-contig
        for (int u = tid; u < BN * (BM / 16); u += 256) {
            int row = u / (BM / 16);
            int seg = u % (BM / 16);
            uint4 v = *(const uint4*)(lds + row * BMP + seg * 16);
            *(uint4*)(outp + (size_t)(n0 + row) * 256 + m0 + seg * 16) = v;
        }
    } else {
        const float c2 = sc[1], c3 = sc[2], cS = sc[3];
        const float* bi3 = (const float*)(wsb + WS_BI3);
        const float* bis = (const float*)(wsb + WS_BIS);
        float* ldsF = (float*)lds;
        constexpr int LDN = BN + 4;
        constexpr int SEGS = BN / 16;
        for (int half = 0; half < 2; half++) {
            __syncthreads();
            if (wm == half * 64) {
#pragma unroll
                for (int i = 0; i < FM; i++) {
                    int mloc = i * 16 + quad * 4;           // within half [0,64)
                    int mg = m0 + half * 64 + mloc;         // global m
                    float bt[4];
#pragma unroll
                    for (int r = 0; r < 4; r++)
                        bt[r] = bi3[mg + r] * (c3 / (127.0f * c2)) + bis[mg + r] * (1.0f / 127.0f);
#pragma unroll
                    for (int j = 0; j < FN; j++) {
                        int nloc = wn + j * 16 + lrow;
#pragma unroll
                        for (int r = 0; r < 4; r++) {
                            float v = (c3 * (float)acc3[i][j][r] + cS * (float)accS[i][j][r])
                                          * (0.5f / 16129.0f) + bt[r];
                            v = v < 0.0f ? 0.0f : (v > 6.0f ? 6.0f : v);  // NaN-propagating
                            ldsF[(mloc + r) * LDN + nloc] = v;
                        }
                    }
                }
            }
            __syncthreads();
            // copy out 64 rows x BN floats (aligned 16B segments along n)
            {
                int rw0 = tid / SEGS, seg = tid % SEGS;
                int nbase = n0 + seg * 16;
                for (int row = rw0; row < 64; row += 256 / SEGS) {
                    const float* src = ldsF + row * LDN + seg * 16;
                    float* dst = dout + ((size_t)bb * 1024 + m0 + half * 64 + row) * 196 + nbase;
                    if (nbase + 16 <= 196) {
                        *(f32x4*)(dst + 0)  = *(const f32x4*)(src + 0);
                        *(f32x4*)(dst + 4)  = *(const f32x4*)(src + 4);
                        *(f32x4*)(dst + 8)  = *(const f32x4*)(src + 8);
                        *(f32x4*)(dst + 12) = *(const f32x4*)(src + 12);
                    } else {
                        for (int q = 0; q < 16 && nbase + q < 196; q++) dst[q] = src[q];
                    }
                }
            }
        }
    }
}

extern "C" void kernel_launch(void* const* d_in, const int* in_sizes, int n_in,
                              void* d_out, int out_size, void* d_ws, size_t ws_size,
                              hipStream_t stream) {
    const float* x   = (const float*)d_in[0];
    const float* w1  = (const float*)d_in[1];
    const float* b1  = (const float*)d_in[2];
    const float* w2  = (const float*)d_in[3];
    const float* b2  = (const float*)d_in[4];
    const float* w3  = (const float*)d_in[5];
    const float* b3  = (const float*)d_in[6];
    const float* wsd = (const float*)d_in[7];
    const float* bs  = (const float*)d_in[8];
    float* out = (float*)d_out;
    char* wsb = (char*)d_ws;

    k_init<<<16, 256, 0, stream>>>((float*)wsb);
    k_maxabs<<<dim3(32, 4), 256, 0, stream>>>(w1, w2, w3, wsd, (float*)(wsb + WS_SCALES));
    k_quant_w<<<dim3(96, 8), 256, 0, stream>>>(w1, w2, w3, wsd, b1, b2, b3, bs, wsb);
    k_quant_x<<<dim3(25, 16, 64), 256, 0, stream>>>(x, (signed char*)(wsb + WS_A0));
    k_conv<0, 128, 128, 2, 2><<<dim3(392, 2, 1), 256, 0, stream>>>(wsb, out);  // conv1
    k_conv<1, 64, 128, 2, 2><<<dim3(98, 4, 1), 256, 0, stream>>>(wsb, out);    // conv2
    k_conv<2, 128, 128, 2, 2><<<dim3(2, 8, 64), 256, 0, stream>>>(wsb, out);   // conv3+sc
}